// Round 14
// baseline (495.867 us; speedup 1.0000x reference)
//
#include <hip/hip_runtime.h>

#define BN_TOT 24576   // B*N
#define NPTS 786432    // BN_TOT*32
#define EPS_ 1e-5f
#define NBLK 2048
#define TOTW (NBLK * 4)   // 8192 waves; 3 polylines per wave exact

typedef float v4f __attribute__((ext_vector_type(4)));
typedef __attribute__((ext_vector_type(8))) short sv8;    // 8 bf16 (4 VGPRs)
typedef __attribute__((ext_vector_type(4))) float fv4;    // MFMA acc
typedef unsigned short u16;
typedef unsigned int u32;

__device__ __forceinline__ v4f ld4(const float* p) { return *(const v4f*)p; }
__device__ __forceinline__ void st4(float* p, v4f v) { *(v4f*)p = v; }

__device__ __forceinline__ float bf2f(u16 u) {
    union { u32 i; float f; } v; v.i = ((u32)u) << 16; return v.f;
}
__device__ __forceinline__ u32 pack2bf(float a, float b) {   // lo=a, hi=b, RNE
    union { float f; u32 i; } x, y; x.f = a; y.f = b;
    u32 xr = x.i + 0x7FFFu + ((x.i >> 16) & 1u);
    u32 yr = y.i + 0x7FFFu + ((y.i >> 16) & 1u);
    return (xr >> 16) | (yr & 0xFFFF0000u);
}

// Workspace S (floats):
// [128..191] sum2 [192..255] sumsq2 [256..319] sum3 [320..383] sumsq3 [384] cnt (fallback)
// [400..444] M (x xT upper-tri 45) [445..453] sum_x (9) [454] cnt_raw
// [512+L*128 ..] scaleL/shiftL (fallback path only)
// H16 at byte offset 8192, ~100.7 MB, TILE-MAJOR (R10-proven):
//   u16 idx(p,ch) = (p&3)*512 + (p>>2)*64 + ch

__global__ void k_finalize(const float* __restrict__ g, const float* __restrict__ b,
                           float* __restrict__ S, int layer) {
    int c = threadIdx.x;
    if (c < 64) {
        float cnt = fmaxf(S[384], 1.f);
        float mean = S[layer * 128 + c] / cnt;
        float var = fmaxf(S[layer * 128 + 64 + c] / cnt - mean * mean, 0.f);
        float sc = g[c] * rsqrtf(var + EPS_);
        float sh = b[c] - mean * sc;
        S[512 + layer * 128 + c] = sc;
        S[512 + layer * 128 + 64 + c] = sh;
    }
}

// ---- moment-based stage-1 stats (R13-proven) -------------------------------
__global__ __launch_bounds__(256) void k_mom(const float* __restrict__ poly,
                                             const int* __restrict__ mask,
                                             float* __restrict__ S) {
    __shared__ float red[4][55];
    const int t = threadIdx.x, wv = t >> 6, lane = t & 63;
    float M[45], sx[9], cc = 0.f;
    #pragma unroll
    for (int i = 0; i < 45; i++) M[i] = 0.f;
    #pragma unroll
    for (int i = 0; i < 9; i++) sx[i] = 0.f;
    for (int idx = blockIdx.x * 256 + t; idx < NPTS; idx += NBLK * 256) {
        float m = (mask[idx] != 0) ? 1.f : 0.f;
        const float* xp = poly + (size_t)idx * 9;
        float x[9];
        #pragma unroll
        for (int j = 0; j < 9; j++) x[j] = xp[j];
        cc += m;
        int k = 0;
        #pragma unroll
        for (int a = 0; a < 9; a++) {
            float xa = x[a] * m;
            sx[a] += xa;
            #pragma unroll
            for (int b2 = a; b2 < 9; b2++) { M[k] += xa * x[b2]; k++; }
        }
    }
    #pragma unroll
    for (int i = 0; i < 45; i++) {
        float v = M[i];
        v += __shfl_xor(v, 1); v += __shfl_xor(v, 2); v += __shfl_xor(v, 4);
        v += __shfl_xor(v, 8); v += __shfl_xor(v, 16); v += __shfl_xor(v, 32);
        M[i] = v;
    }
    #pragma unroll
    for (int i = 0; i < 9; i++) {
        float v = sx[i];
        v += __shfl_xor(v, 1); v += __shfl_xor(v, 2); v += __shfl_xor(v, 4);
        v += __shfl_xor(v, 8); v += __shfl_xor(v, 16); v += __shfl_xor(v, 32);
        sx[i] = v;
    }
    {
        float v = cc;
        v += __shfl_xor(v, 1); v += __shfl_xor(v, 2); v += __shfl_xor(v, 4);
        v += __shfl_xor(v, 8); v += __shfl_xor(v, 16); v += __shfl_xor(v, 32);
        cc = v;
    }
    if (lane == 0) {
        #pragma unroll
        for (int i = 0; i < 45; i++) red[wv][i] = M[i];
        #pragma unroll
        for (int i = 0; i < 9; i++) red[wv][45 + i] = sx[i];
        red[wv][54] = cc;
    }
    __syncthreads();
    if (t < 55) atomicAdd(&S[400 + t], red[0][t] + red[1][t] + red[2][t] + red[3][t]);
}

__global__ void k_finalize_mom(const float* __restrict__ Wpre,
                               const float* __restrict__ g, const float* __restrict__ b,
                               float* __restrict__ S) {
    int c = threadIdx.x;
    if (c < 64) {
        float w[9];
        #pragma unroll
        for (int j = 0; j < 9; j++) w[j] = Wpre[c * 9 + j];
        float cnt = fmaxf(S[454], 1.f);
        float s1 = 0.f;
        #pragma unroll
        for (int j = 0; j < 9; j++) s1 += w[j] * S[445 + j];
        float s2 = 0.f;
        int k = 0;
        #pragma unroll
        for (int a = 0; a < 9; a++)
            #pragma unroll
            for (int b2 = a; b2 < 9; b2++) {
                float mm = S[400 + k];
                s2 += (a == b2) ? w[a] * w[a] * mm : 2.f * w[a] * w[b2] * mm;
                k++;
            }
        float mean = s1 / cnt;
        float var = fmaxf(s2 / cnt - mean * mean, 0.f);
        float sc = g[c] * rsqrtf(var + EPS_);
        float sh = b[c] - mean * sc;
        S[512 + c] = sc;
        S[576 + c] = sh;
        if (c == 0) S[384] = S[454];
    }
}

// ---- shared helpers --------------------------------------------------------
__device__ __forceinline__ void mm_acc(float a[4][8], v4f av, v4f w0, v4f w1) {
    #pragma unroll
    for (int i = 0; i < 4; i++) {
        #pragma unroll
        for (int j = 0; j < 4; j++) {
            a[i][j] += av[i] * w0[j];
            a[i][4 + j] += av[i] * w1[j];
        }
    }
}

__device__ __forceinline__ void tzero(float a[4][8]) {
    #pragma unroll
    for (int i = 0; i < 4; i++)
        #pragma unroll
        for (int j = 0; j < 8; j++) a[i][j] = 0.f;
}

__device__ __forceinline__ void load_x(const float* xg, float* xTw, int lane) {
    for (int e = lane; e < 288; e += 64) {
        float v = xg[e];
        int p = e / 9, c = e - 9 * p;
        xTw[c * 36 + p] = v;
    }
}

__device__ __forceinline__ void stage1(const float* xTw, const float* WpT,
                                       int pg, int cg, float a1[4][8]) {
    tzero(a1);
    #pragma unroll
    for (int k = 0; k < 9; k++) {
        v4f av = ld4(xTw + k * 36 + 4 * pg);
        v4f w0 = ld4(WpT + k * 64 + 8 * cg);
        v4f w1 = ld4(WpT + k * 64 + 8 * cg + 4);
        mm_acc(a1, av, w0, w1);
    }
}

__device__ __forceinline__ void gemv64(const float* actw, const float* WT,
                                       int pg, int cg, float a[4][8]) {
    #pragma unroll 8
    for (int k = 0; k < 64; k++) {
        v4f av = ld4(actw + k * 32 + 4 * (pg ^ (k >> 3)));
        v4f w0 = ld4(WT + k * 64 + 8 * cg);
        v4f w1 = ld4(WT + k * 64 + 8 * cg + 4);
        mm_acc(a, av, w0, w1);
    }
}

__device__ __forceinline__ void bn_store_act(float* actw, const float a[4][8],
                                             const float* sc, const float* sh,
                                             const float m[4], int pg, int cg,
                                             float f[4][8]) {
    #pragma unroll
    for (int j = 0; j < 8; j++) {
        v4f v;
        #pragma unroll
        for (int i = 0; i < 4; i++) {
            float x = fmaxf(a[i][j] * sc[j] + sh[j], 0.f) * m[i];
            v[i] = x; f[i][j] = x;
        }
        st4(actw + (8 * cg + j) * 32 + 4 * (pg ^ cg), v);
    }
}

__device__ __forceinline__ void pool_reduce(const float f[4][8], float pmax[8]) {
    #pragma unroll
    for (int j = 0; j < 8; j++) {
        float v = fmaxf(fmaxf(f[0][j], f[1][j]), fmaxf(f[2][j], f[3][j]));
        v = fmaxf(v, __shfl_xor(v, 8));
        v = fmaxf(v, __shfl_xor(v, 16));
        v = fmaxf(v, __shfl_xor(v, 32));
        pmax[j] = v;
    }
}

__device__ __forceinline__ void qa_glob(const float pmax[8], const float* W1,
                                        float* pbufw, int pg, int cg, float qa[8]) {
    if (pg == 0)
        #pragma unroll
        for (int j = 0; j < 8; j++) pbufw[8 * cg + j] = pmax[j];
    __builtin_amdgcn_wave_barrier();
    #pragma unroll
    for (int j = 0; j < 8; j++) qa[j] = 0.f;
    #pragma unroll 4
    for (int kk = 0; kk < 16; kk++) {
        float p0 = pbufw[4 * kk], p1 = pbufw[4 * kk + 1];
        float p2 = pbufw[4 * kk + 2], p3 = pbufw[4 * kk + 3];
        #pragma unroll
        for (int j = 0; j < 8; j++) {
            v4f w = ld4(W1 + (8 * cg + j) * 128 + 64 + 4 * kk);
            qa[j] += w[0] * p0 + w[1] * p1 + w[2] * p2 + w[3] * p3;
        }
    }
}

__device__ __forceinline__ void stats_acc(const float a[4][8], const float m[4],
                                          float sp[8], float ssp[8]) {
    #pragma unroll
    for (int i = 0; i < 4; i++)
        #pragma unroll
        for (int j = 0; j < 8; j++) {
            float hv = a[i][j] * m[i];
            sp[j] += hv; ssp[j] += hv * a[i][j];
        }
}

__device__ __forceinline__ void stats_flush(float sp[8], float ssp[8],
                                            float (*red_s)[64], float (*red_ss)[64],
                                            float* S, int base, int t, int wv,
                                            int pg, int cg) {
    #pragma unroll
    for (int j = 0; j < 8; j++) {
        float v = sp[j];
        v += __shfl_xor(v, 8); v += __shfl_xor(v, 16); v += __shfl_xor(v, 32);
        sp[j] = v;
        float w = ssp[j];
        w += __shfl_xor(w, 8); w += __shfl_xor(w, 16); w += __shfl_xor(w, 32);
        ssp[j] = w;
    }
    if (pg == 0)
        #pragma unroll
        for (int j = 0; j < 8; j++) { red_s[wv][8 * cg + j] = sp[j]; red_ss[wv][8 * cg + j] = ssp[j]; }
    __syncthreads();
    if (t < 64) {
        atomicAdd(&S[base + t], red_s[0][t] + red_s[1][t] + red_s[2][t] + red_s[3][t]);
        atomicAdd(&S[base + 64 + t], red_ss[0][t] + red_ss[1][t] + red_ss[2][t] + red_ss[3][t]);
    }
}

// ---- pass 2 (big ws): full-MFMA stats2 with inlined BN1 finalize -----------
// Stage1 MFMA: A=Wpre (K padded 9->32), B=x^T. Stage2: A=W1 (K=128), B=[feat;pooled].
// Layouts (HW-validated): A[m=lane&15][k=quad*8+j], B[k=quad*8+j][n=lane&15],
// C: col(n)=lane&15, row(m)=mt*16+quad*4+r.
__global__ __launch_bounds__(256) void k_stats2_mfma(const float* __restrict__ poly,
                                                     const int* __restrict__ mask,
                                                     const float* __restrict__ Wpre,
                                                     const float* __restrict__ gpre,
                                                     const float* __restrict__ bpre,
                                                     const float* __restrict__ W1,
                                                     float* __restrict__ S,
                                                     u16* __restrict__ H16) {
    __shared__ __align__(16) float xT[4][324];
    __shared__ u16 h1b[4][32 * 68];
    __shared__ __align__(16) float pbuf[4][64];
    __shared__ float scsh[128];
    __shared__ float red_s[4][64], red_ss[4][64];
    const int t = threadIdx.x, wv = t >> 6, lane = t & 63;
    const int n = lane & 15, quad = lane >> 4;

    // inline BN1 finalize from moments
    if (t < 64) {
        float w[9];
        #pragma unroll
        for (int j = 0; j < 9; j++) w[j] = Wpre[t * 9 + j];
        float cnt = fmaxf(S[454], 1.f);
        float s1 = 0.f;
        #pragma unroll
        for (int j = 0; j < 9; j++) s1 += w[j] * S[445 + j];
        float s2 = 0.f;
        int k = 0;
        #pragma unroll
        for (int a = 0; a < 9; a++)
            #pragma unroll
            for (int b2 = a; b2 < 9; b2++) {
                float mm = S[400 + k];
                s2 += (a == b2) ? w[a] * w[a] * mm : 2.f * w[a] * w[b2] * mm;
                k++;
            }
        float mean = s1 / cnt;
        float var = fmaxf(s2 / cnt - mean * mean, 0.f);
        float sc = gpre[t] * rsqrtf(var + EPS_);
        scsh[t] = sc;
        scsh[64 + t] = bpre[t] - mean * sc;
    }

    // A-frags: Wpre padded to K=32
    sv8 awp[4];
    #pragma unroll
    for (int mt = 0; mt < 4; mt++) {
        union { sv8 v; u32 w[4]; } uu;
        #pragma unroll
        for (int d = 0; d < 4; d++) uu.w[d] = 0u;
        if (quad == 0) {
            const float* wr = Wpre + (mt * 16 + n) * 9;
            #pragma unroll
            for (int d = 0; d < 4; d++) uu.w[d] = pack2bf(wr[2 * d], wr[2 * d + 1]);
        } else if (quad == 1) {
            uu.w[0] = pack2bf(Wpre[(mt * 16 + n) * 9 + 8], 0.f);
        }
        awp[mt] = uu.v;
    }
    // A-frags: W1 (K=128)
    sv8 aw[4][4];
    #pragma unroll
    for (int mt = 0; mt < 4; mt++)
        #pragma unroll
        for (int ss = 0; ss < 4; ss++) {
            const float* wr = W1 + (size_t)(mt * 16 + n) * 128 + ss * 32 + quad * 8;
            union { sv8 v; u32 w[4]; } uu;
            #pragma unroll
            for (int d = 0; d < 4; d++) uu.w[d] = pack2bf(wr[2 * d], wr[2 * d + 1]);
            aw[mt][ss] = uu.v;
        }
    __syncthreads();
    // BN1 consts in C layout: channel = mt*16 + quad*4 + r
    float scC[16], shC[16];
    #pragma unroll
    for (int mt = 0; mt < 4; mt++)
        #pragma unroll
        for (int r = 0; r < 4; r++) {
            int ch = mt * 16 + quad * 4 + r;
            scC[mt * 4 + r] = scsh[ch];
            shC[mt * 4 + r] = scsh[64 + ch];
        }

    float sp16[16], ssp16[16];
    #pragma unroll
    for (int e = 0; e < 16; e++) { sp16[e] = 0.f; ssp16[e] = 0.f; }

    const int wgid = blockIdx.x * 4 + wv;
    for (int bn = wgid; bn < BN_TOT; bn += TOTW) {
        float mv = (lane < 32 && mask[bn * 32 + lane] != 0) ? 1.f : 0.f;
        load_x(poly + (size_t)bn * 288, xT[wv], lane);
        __builtin_amdgcn_wave_barrier();
        float mp0 = __shfl(mv, n), mp1 = __shfl(mv, 16 + n);
        float mpn[2] = {mp0, mp1};

        // x B-frags (K padded to 32)
        sv8 bx[2];
        #pragma unroll
        for (int nt = 0; nt < 2; nt++) {
            int p = nt * 16 + n;
            float xv[8];
            #pragma unroll
            for (int j = 0; j < 8; j++) {
                int k = quad * 8 + j;
                xv[j] = (k < 9) ? xT[wv][k * 36 + p] : 0.f;
            }
            union { sv8 v; u32 w[4]; } uu;
            #pragma unroll
            for (int d = 0; d < 4; d++) uu.w[d] = pack2bf(xv[2 * d], xv[2 * d + 1]);
            bx[nt] = uu.v;
        }
        // stage1 MFMA -> h_pre in C layout
        fv4 accp[4][2];
        #pragma unroll
        for (int mt = 0; mt < 4; mt++)
            #pragma unroll
            for (int nt = 0; nt < 2; nt++) {
                fv4 z; z[0] = 0.f; z[1] = 0.f; z[2] = 0.f; z[3] = 0.f;
                accp[mt][nt] = __builtin_amdgcn_mfma_f32_16x16x32_bf16(awp[mt], bx[nt], z, 0, 0, 0);
            }
        // BN1 + relu + mask (C layout)
        float fC[4][2][4];
        #pragma unroll
        for (int mt = 0; mt < 4; mt++)
            #pragma unroll
            for (int nt = 0; nt < 2; nt++)
                #pragma unroll
                for (int r = 0; r < 4; r++)
                    fC[mt][nt][r] = fmaxf(accp[mt][nt][r] * scC[mt * 4 + r] + shC[mt * 4 + r], 0.f) * mpn[nt];
        // pooled (reduce over nt + n-lanes), write to pbuf
        #pragma unroll
        for (int mt = 0; mt < 4; mt++)
            #pragma unroll
            for (int r = 0; r < 4; r++) {
                float v = fmaxf(fC[mt][0][r], fC[mt][1][r]);
                v = fmaxf(v, __shfl_xor(v, 1));
                v = fmaxf(v, __shfl_xor(v, 2));
                v = fmaxf(v, __shfl_xor(v, 4));
                v = fmaxf(v, __shfl_xor(v, 8));
                if (n == 0) pbuf[wv][mt * 16 + quad * 4 + r] = v;
            }
        // feat C->B relayout via LDS bounce
        #pragma unroll
        for (int nt = 0; nt < 2; nt++) {
            int p = nt * 16 + n;
            #pragma unroll
            for (int mt = 0; mt < 4; mt++) {
                uint2 pk;
                pk.x = pack2bf(fC[mt][nt][0], fC[mt][nt][1]);
                pk.y = pack2bf(fC[mt][nt][2], fC[mt][nt][3]);
                *(uint2*)&h1b[wv][p * 68 + mt * 16 + quad * 4] = pk;
            }
        }
        __builtin_amdgcn_wave_barrier();
        sv8 bg0[2], bg1[2], bp[2];
        #pragma unroll
        for (int s = 0; s < 2; s++) {
            uint4 v0 = *(const uint4*)&h1b[wv][n * 68 + s * 32 + quad * 8];
            uint4 v1 = *(const uint4*)&h1b[wv][(16 + n) * 68 + s * 32 + quad * 8];
            union { sv8 v; uint4 q; } a, b;
            a.q = v0; b.q = v1;
            bg0[s] = a.v; bg1[s] = b.v;
            v4f pa = ld4(&pbuf[wv][s * 32 + quad * 8]);
            v4f pb = ld4(&pbuf[wv][s * 32 + quad * 8 + 4]);
            union { sv8 v; u32 w[4]; } c;
            c.w[0] = pack2bf(pa[0], pa[1]);
            c.w[1] = pack2bf(pa[2], pa[3]);
            c.w[2] = pack2bf(pb[0], pb[1]);
            c.w[3] = pack2bf(pb[2], pb[3]);
            bp[s] = c.v;
        }
        __builtin_amdgcn_wave_barrier();
        // stage2 MFMA: h1 = W1 @ [feat; pooled]
        fv4 acc[4][2];
        #pragma unroll
        for (int mt = 0; mt < 4; mt++) {
            #pragma unroll
            for (int nt = 0; nt < 2; nt++) { acc[mt][nt][0] = 0.f; acc[mt][nt][1] = 0.f; acc[mt][nt][2] = 0.f; acc[mt][nt][3] = 0.f; }
            acc[mt][0] = __builtin_amdgcn_mfma_f32_16x16x32_bf16(aw[mt][0], bg0[0], acc[mt][0], 0, 0, 0);
            acc[mt][0] = __builtin_amdgcn_mfma_f32_16x16x32_bf16(aw[mt][1], bg0[1], acc[mt][0], 0, 0, 0);
            acc[mt][0] = __builtin_amdgcn_mfma_f32_16x16x32_bf16(aw[mt][2], bp[0], acc[mt][0], 0, 0, 0);
            acc[mt][0] = __builtin_amdgcn_mfma_f32_16x16x32_bf16(aw[mt][3], bp[1], acc[mt][0], 0, 0, 0);
            acc[mt][1] = __builtin_amdgcn_mfma_f32_16x16x32_bf16(aw[mt][0], bg1[0], acc[mt][1], 0, 0, 0);
            acc[mt][1] = __builtin_amdgcn_mfma_f32_16x16x32_bf16(aw[mt][1], bg1[1], acc[mt][1], 0, 0, 0);
            acc[mt][1] = __builtin_amdgcn_mfma_f32_16x16x32_bf16(aw[mt][2], bp[0], acc[mt][1], 0, 0, 0);
            acc[mt][1] = __builtin_amdgcn_mfma_f32_16x16x32_bf16(aw[mt][3], bp[1], acc[mt][1], 0, 0, 0);
        }
        // stats + h1 LDS bounce + tile-major global store
        #pragma unroll
        for (int nt = 0; nt < 2; nt++) {
            int p = nt * 16 + n;
            float mp = mpn[nt];
            #pragma unroll
            for (int mt = 0; mt < 4; mt++) {
                #pragma unroll
                for (int r = 0; r < 4; r++) {
                    float hv = acc[mt][nt][r];
                    sp16[mt * 4 + r] += hv * mp;
                    ssp16[mt * 4 + r] += hv * hv * mp;
                }
                uint2 pk;
                pk.x = pack2bf(acc[mt][nt][0], acc[mt][nt][1]);
                pk.y = pack2bf(acc[mt][nt][2], acc[mt][nt][3]);
                *(uint2*)&h1b[wv][p * 68 + mt * 16 + quad * 4] = pk;
            }
        }
        __builtin_amdgcn_wave_barrier();
        u16* Hw = H16 + (size_t)bn * 2048;
        #pragma unroll
        for (int i = 0; i < 4; i++) {
            int p = 4 * (lane >> 3) + i;
            int chb = 8 * (lane & 7);
            uint4 v = *(const uint4*)&h1b[wv][p * 68 + chb];
            *(uint4*)(Hw + i * 512 + lane * 8) = v;
        }
        __builtin_amdgcn_wave_barrier();
    }
    #pragma unroll
    for (int e = 0; e < 16; e++) {
        float v = sp16[e];
        v += __shfl_xor(v, 1); v += __shfl_xor(v, 2); v += __shfl_xor(v, 4); v += __shfl_xor(v, 8);
        sp16[e] = v;
        float w = ssp16[e];
        w += __shfl_xor(w, 1); w += __shfl_xor(w, 2); w += __shfl_xor(w, 4); w += __shfl_xor(w, 8);
        ssp16[e] = w;
    }
    if (n == 0) {
        #pragma unroll
        for (int mt = 0; mt < 4; mt++)
            #pragma unroll
            for (int r = 0; r < 4; r++) {
                red_s[wv][mt * 16 + quad * 4 + r] = sp16[mt * 4 + r];
                red_ss[wv][mt * 16 + quad * 4 + r] = ssp16[mt * 4 + r];
            }
    }
    __syncthreads();
    if (t < 64) {
        atomicAdd(&S[128 + t], red_s[0][t] + red_s[1][t] + red_s[2][t] + red_s[3][t]);
        atomicAdd(&S[128 + 64 + t], red_ss[0][t] + red_ss[1][t] + red_ss[2][t] + red_ss[3][t]);
    }
}

// ---- pass 3 (big ws): MFMA stats3 with inlined BN2 finalize ----------------
__global__ __launch_bounds__(256) void k_stats3_mfma(const int* __restrict__ mask,
                                                     const float* __restrict__ g1,
                                                     const float* __restrict__ b1,
                                                     const float* __restrict__ W2,
                                                     float* __restrict__ S,
                                                     u16* __restrict__ H16) {
    __shared__ u16 h2b[4][32 * 68];
    __shared__ float scsh[128];
    __shared__ float red_s[4][64], red_ss[4][64];
    const int t = threadIdx.x, wv = t >> 6, lane = t & 63;
    const int n = lane & 15, quad = lane >> 4;

    if (t < 64) {
        float cnt = fmaxf(S[454], 1.f);
        float mean = S[128 + t] / cnt;
        float var = fmaxf(S[192 + t] / cnt - mean * mean, 0.f);
        float sc = g1[t] * rsqrtf(var + EPS_);
        scsh[t] = sc;
        scsh[64 + t] = b1[t] - mean * sc;
    }

    sv8 aw[4][2];
    #pragma unroll
    for (int mt = 0; mt < 4; mt++)
        #pragma unroll
        for (int s = 0; s < 2; s++) {
            const float* wr = W2 + (mt * 16 + n) * 64 + s * 32 + quad * 8;
            union { sv8 v; u32 w[4]; } uu;
            #pragma unroll
            for (int d = 0; d < 4; d++) uu.w[d] = pack2bf(wr[2 * d], wr[2 * d + 1]);
            aw[mt][s] = uu.v;
        }
    __syncthreads();
    float sck[16], shk[16];
    #pragma unroll
    for (int s = 0; s < 2; s++)
        #pragma unroll
        for (int j = 0; j < 8; j++) {
            int k = s * 32 + quad * 8 + j;
            sck[s * 8 + j] = scsh[k];
            shk[s * 8 + j] = scsh[64 + k];
        }

    float sp16[16], ssp16[16];
    #pragma unroll
    for (int e = 0; e < 16; e++) { sp16[e] = 0.f; ssp16[e] = 0.f; }

    const int wgid = blockIdx.x * 4 + wv;
    for (int bn = wgid; bn < BN_TOT; bn += TOTW) {
        float mv = (lane < 32 && mask[bn * 32 + lane] != 0) ? 1.f : 0.f;
        const u16* Hb = H16 + (size_t)bn * 2048;
        fv4 acc[4][2];
        #pragma unroll
        for (int mt = 0; mt < 4; mt++)
            #pragma unroll
            for (int nt = 0; nt < 2; nt++) { acc[mt][nt][0] = 0.f; acc[mt][nt][1] = 0.f; acc[mt][nt][2] = 0.f; acc[mt][nt][3] = 0.f; }
        float mpn[2];
        #pragma unroll
        for (int nt = 0; nt < 2; nt++) {
            int p = nt * 16 + n;
            float mp = __shfl(mv, p);
            mpn[nt] = mp;
            sv8 bg[2];
            #pragma unroll
            for (int s = 0; s < 2; s++) {
                int base = (p & 3) * 512 + (p >> 2) * 64 + s * 32 + quad * 8;
                uint4 hw = *(const uint4*)(Hb + base);
                u32 ws[4] = {hw.x, hw.y, hw.z, hw.w};
                union { sv8 v; u32 w[4]; } uu;
                #pragma unroll
                for (int d = 0; d < 4; d++) {
                    union { u32 u; float f; } lo, hi;
                    lo.u = ws[d] << 16; hi.u = ws[d] & 0xFFFF0000u;
                    float g0 = fmaxf(lo.f * sck[s * 8 + 2 * d] + shk[s * 8 + 2 * d], 0.f) * mp;
                    float g1v = fmaxf(hi.f * sck[s * 8 + 2 * d + 1] + shk[s * 8 + 2 * d + 1], 0.f) * mp;
                    uu.w[d] = pack2bf(g0, g1v);
                }
                bg[s] = uu.v;
            }
            #pragma unroll
            for (int mt = 0; mt < 4; mt++) {
                acc[mt][nt] = __builtin_amdgcn_mfma_f32_16x16x32_bf16(aw[mt][0], bg[0], acc[mt][nt], 0, 0, 0);
                acc[mt][nt] = __builtin_amdgcn_mfma_f32_16x16x32_bf16(aw[mt][1], bg[1], acc[mt][nt], 0, 0, 0);
            }
        }
        #pragma unroll
        for (int nt = 0; nt < 2; nt++) {
            int p = nt * 16 + n;
            float mp = mpn[nt];
            #pragma unroll
            for (int mt = 0; mt < 4; mt++) {
                #pragma unroll
                for (int r = 0; r < 4; r++) {
                    float hv = acc[mt][nt][r];
                    sp16[mt * 4 + r] += hv * mp;
                    ssp16[mt * 4 + r] += hv * hv * mp;
                }
                uint2 pk;
                pk.x = pack2bf(acc[mt][nt][0], acc[mt][nt][1]);
                pk.y = pack2bf(acc[mt][nt][2], acc[mt][nt][3]);
                *(uint2*)&h2b[wv][p * 68 + mt * 16 + quad * 4] = pk;
            }
        }
        __builtin_amdgcn_wave_barrier();
        u16* Hw = H16 + (size_t)bn * 2048;
        #pragma unroll
        for (int i = 0; i < 4; i++) {
            int p = 4 * (lane >> 3) + i;
            int chb = 8 * (lane & 7);
            uint4 v = *(const uint4*)&h2b[wv][p * 68 + chb];
            *(uint4*)(Hw + i * 512 + lane * 8) = v;
        }
        __builtin_amdgcn_wave_barrier();
    }
    #pragma unroll
    for (int e = 0; e < 16; e++) {
        float v = sp16[e];
        v += __shfl_xor(v, 1); v += __shfl_xor(v, 2); v += __shfl_xor(v, 4); v += __shfl_xor(v, 8);
        sp16[e] = v;
        float w = ssp16[e];
        w += __shfl_xor(w, 1); w += __shfl_xor(w, 2); w += __shfl_xor(w, 4); w += __shfl_xor(w, 8);
        ssp16[e] = w;
    }
    if (n == 0) {
        #pragma unroll
        for (int mt = 0; mt < 4; mt++)
            #pragma unroll
            for (int r = 0; r < 4; r++) {
                red_s[wv][mt * 16 + quad * 4 + r] = sp16[mt * 4 + r];
                red_ss[wv][mt * 16 + quad * 4 + r] = ssp16[mt * 4 + r];
            }
    }
    __syncthreads();
    if (t < 64) {
        atomicAdd(&S[256 + t], red_s[0][t] + red_s[1][t] + red_s[2][t] + red_s[3][t]);
        atomicAdd(&S[256 + 64 + t], red_ss[0][t] + red_ss[1][t] + red_ss[2][t] + red_ss[3][t]);
    }
}

// ---- pass 4 (big ws): out with inlined BN3 finalize ------------------------
__global__ __launch_bounds__(256) void k_out_load(const int* __restrict__ mask,
                                                  const float* __restrict__ g2,
                                                  const float* __restrict__ b2,
                                                  const float* __restrict__ Wo1,
                                                  const float* __restrict__ bo1,
                                                  const float* __restrict__ Wo2,
                                                  const float* __restrict__ bo2,
                                                  const float* __restrict__ S,
                                                  const u16* __restrict__ H16,
                                                  float* __restrict__ out) {
    __shared__ __align__(16) float Wo1T[4096];
    __shared__ __align__(16) float Wo2T[8192];
    __shared__ float pbuf[4][64];
    __shared__ float scsh[128];
    const int t = threadIdx.x, wv = t >> 6, lane = t & 63;
    if (t < 64) {
        float cnt = fmaxf(S[454], 1.f);
        float mean = S[256 + t] / cnt;
        float var = fmaxf(S[320 + t] / cnt - mean * mean, 0.f);
        float sc = g2[t] * rsqrtf(var + EPS_);
        scsh[t] = sc;
        scsh[64 + t] = b2[t] - mean * sc;
    }
    for (int i = t; i < 4096; i += 256) { int k = i >> 6, ch = i & 63; Wo1T[i] = Wo1[ch * 64 + k]; }
    for (int i = t; i < 8192; i += 256) { int k = i >> 7, o = i & 127; Wo2T[i] = Wo2[o * 64 + k]; }
    __syncthreads();
    float sc3 = scsh[lane], sh3 = scsh[64 + lane];
    float bo1v = bo1[lane], bo2a = bo2[lane], bo2b = bo2[64 + lane];
    const int wgid = blockIdx.x * 4 + wv;
    for (int bn = wgid; bn < BN_TOT; bn += TOTW) {
        float mv = (lane < 32 && mask[bn * 32 + lane] != 0) ? 1.f : 0.f;
        float vf = __ballot(mv > 0.5f) ? 1.f : 0.f;
        const u16* Hb16 = H16 + (size_t)bn * 2048;
        float mx = 0.f;
        #pragma unroll
        for (int i = 0; i < 4; i++)
            #pragma unroll
            for (int pgx = 0; pgx < 8; pgx++) {
                float h = bf2f(Hb16[i * 512 + pgx * 64 + lane]);
                float mp = __shfl(mv, 4 * pgx + i);
                mx = fmaxf(mx, fmaxf(h * sc3 + sh3, 0.f) * mp);
            }
        pbuf[wv][lane] = mx;
        __builtin_amdgcn_wave_barrier();
        float y1 = bo1v;
        #pragma unroll 8
        for (int k = 0; k < 64; k++) y1 += Wo1T[k * 64 + lane] * pbuf[wv][k];
        y1 = fmaxf(y1, 0.f);
        pbuf[wv][lane] = y1;
        __builtin_amdgcn_wave_barrier();
        float o0 = bo2a, o1 = bo2b;
        #pragma unroll 8
        for (int k = 0; k < 64; k++) {
            float yv = pbuf[wv][k];
            o0 += Wo2T[k * 128 + lane] * yv;
            o1 += Wo2T[k * 128 + 64 + lane] * yv;
        }
        out[(size_t)bn * 128 + lane] = o0 * vf;
        out[(size_t)bn * 128 + 64 + lane] = o1 * vf;
        __builtin_amdgcn_wave_barrier();
    }
}

// ---- fallback (small ws): recompute path, untouched ------------------------
__device__ __forceinline__ void qa_lds_fb(const float pmax[8], const float* W1pT,
                                          int cg, float qa[8]) {
    #pragma unroll
    for (int j = 0; j < 8; j++) qa[j] = 0.f;
    #pragma unroll
    for (int k = 0; k < 64; k++) {
        float pv = __shfl(pmax[k & 7], k >> 3);
        v4f w0 = ld4(W1pT + k * 64 + 8 * cg);
        v4f w1 = ld4(W1pT + k * 64 + 8 * cg + 4);
        #pragma unroll
        for (int j = 0; j < 4; j++) { qa[j] += pv * w0[j]; qa[4 + j] += pv * w1[j]; }
    }
}

__global__ __launch_bounds__(256) void k_stats2_fb(const float* __restrict__ poly,
                                                   const int* __restrict__ mask,
                                                   const float* __restrict__ Wpre,
                                                   const float* __restrict__ W1,
                                                   float* __restrict__ S) {
    __shared__ __align__(16) float WpT[576];
    __shared__ __align__(16) float W1aT[4096];
    __shared__ __align__(16) float W1pT[4096];
    __shared__ __align__(16) float act[4][2048];
    __shared__ __align__(16) float xT[4][324];
    __shared__ float red_s[4][64], red_ss[4][64];
    const int t = threadIdx.x, wv = t >> 6, lane = t & 63;
    const int pg = lane >> 3, cg = lane & 7;
    for (int i = t; i < 576; i += 256) { int c = i >> 6, ch = i & 63; WpT[i] = Wpre[ch * 9 + c]; }
    for (int i = t; i < 4096; i += 256) {
        int k = i >> 6, ch = i & 63;
        W1aT[i] = W1[ch * 128 + k];
        W1pT[i] = W1[ch * 128 + 64 + k];
    }
    __syncthreads();
    float sc1[8], sh1[8];
    #pragma unroll
    for (int j = 0; j < 8; j++) { sc1[j] = S[512 + 8 * cg + j]; sh1[j] = S[576 + 8 * cg + j]; }
    float sp[8] = {0}, ssp[8] = {0};
    const int wgid = blockIdx.x * 4 + wv;
    for (int bn = wgid; bn < BN_TOT; bn += TOTW) {
        float mv = (lane < 32 && mask[bn * 32 + lane] != 0) ? 1.f : 0.f;
        float m[4];
        #pragma unroll
        for (int i = 0; i < 4; i++) m[i] = __shfl(mv, 4 * pg + i);
        load_x(poly + (size_t)bn * 288, xT[wv], lane);
        __builtin_amdgcn_wave_barrier();
        float a1[4][8], f[4][8];
        stage1(xT[wv], WpT, pg, cg, a1);
        bn_store_act(act[wv], a1, sc1, sh1, m, pg, cg, f);
        float pmax[8], qa[8];
        pool_reduce(f, pmax);
        qa_lds_fb(pmax, W1pT, cg, qa);
        __builtin_amdgcn_wave_barrier();
        float a2[4][8];
        #pragma unroll
        for (int i = 0; i < 4; i++)
            #pragma unroll
            for (int j = 0; j < 8; j++) a2[i][j] = qa[j];
        gemv64(act[wv], W1aT, pg, cg, a2);
        stats_acc(a2, m, sp, ssp);
        __builtin_amdgcn_wave_barrier();
    }
    stats_flush(sp, ssp, red_s, red_ss, S, 128, t, wv, pg, cg);
}

template<bool DO_OUT>
__global__ __launch_bounds__(256) void k_rec34(const float* __restrict__ poly,
                                               const int* __restrict__ mask,
                                               const float* __restrict__ Wpre,
                                               const float* __restrict__ W1,
                                               const float* __restrict__ W2,
                                               const float* __restrict__ Wo1,
                                               const float* __restrict__ bo1,
                                               const float* __restrict__ Wo2,
                                               const float* __restrict__ bo2,
                                               float* __restrict__ S,
                                               float* __restrict__ out) {
    __shared__ __align__(16) float WpT[576];
    __shared__ __align__(16) float W1aT[4096];
    __shared__ __align__(16) float W2T[4096];
    __shared__ __align__(16) float act[4][2048];
    __shared__ __align__(16) float xT[4][324];
    __shared__ float pbuf[4][64];
    __shared__ float red_s[4][64], red_ss[4][64];
    const int t = threadIdx.x, wv = t >> 6, lane = t & 63;
    const int pg = lane >> 3, cg = lane & 7;
    for (int i = t; i < 576; i += 256) { int c = i >> 6, ch = i & 63; WpT[i] = Wpre[ch * 9 + c]; }
    for (int i = t; i < 4096; i += 256) {
        int k = i >> 6, ch = i & 63;
        W1aT[i] = W1[ch * 128 + k];
        W2T[i] = W2[ch * 64 + k];
    }
    __syncthreads();
    float sc1[8], sh1[8], sc2[8], sh2[8], sc3[8], sh3[8];
    #pragma unroll
    for (int j = 0; j < 8; j++) {
        sc1[j] = S[512 + 8 * cg + j]; sh1[j] = S[576 + 8 * cg + j];
        sc2[j] = S[640 + 8 * cg + j]; sh2[j] = S[704 + 8 * cg + j];
    }
    if constexpr (DO_OUT)
        #pragma unroll
        for (int j = 0; j < 8; j++) { sc3[j] = S[768 + 8 * cg + j]; sh3[j] = S[832 + 8 * cg + j]; }
    float bo1v = 0.f, bo2a = 0.f, bo2b = 0.f;
    if constexpr (DO_OUT) { bo1v = bo1[lane]; bo2a = bo2[lane]; bo2b = bo2[64 + lane]; }
    float sp[8] = {0}, ssp[8] = {0};
    const int wgid = blockIdx.x * 4 + wv;
    for (int bn = wgid; bn < BN_TOT; bn += TOTW) {
        float mv = (lane < 32 && mask[bn * 32 + lane] != 0) ? 1.f : 0.f;
        float m[4];
        #pragma unroll
        for (int i = 0; i < 4; i++) m[i] = __shfl(mv, 4 * pg + i);
        load_x(poly + (size_t)bn * 288, xT[wv], lane);
        __builtin_amdgcn_wave_barrier();
        float a1[4][8], f[4][8];
        stage1(xT[wv], WpT, pg, cg, a1);
        bn_store_act(act[wv], a1, sc1, sh1, m, pg, cg, f);
        float pmax[8], qa[8];
        pool_reduce(f, pmax);
        qa_glob(pmax, W1, pbuf[wv], pg, cg, qa);
        __builtin_amdgcn_wave_barrier();
        float a2[4][8];
        #pragma unroll
        for (int i = 0; i < 4; i++)
            #pragma unroll
            for (int j = 0; j < 8; j++) a2[i][j] = qa[j];
        gemv64(act[wv], W1aT, pg, cg, a2);
        __builtin_amdgcn_wave_barrier();
        bn_store_act(act[wv], a2, sc2, sh2, m, pg, cg, f);
        __builtin_amdgcn_wave_barrier();
        float a3[4][8];
        tzero(a3);
        gemv64(act[wv], W2T, pg, cg, a3);
        if constexpr (!DO_OUT) {
            stats_acc(a3, m, sp, ssp);
        } else {
            float px[8];
            #pragma unroll
            for (int j = 0; j < 8; j++) {
                float v = 0.f;
                #pragma unroll
                for (int i = 0; i < 4; i++)
                    v = fmaxf(v, fmaxf(a3[i][j] * sc3[j] + sh3[j], 0.f) * m[i]);
                px[j] = v;
            }
            #pragma unroll
            for (int j = 0; j < 8; j++) {
                float v = px[j];
                v = fmaxf(v, __shfl_xor(v, 8));
                v = fmaxf(v, __shfl_xor(v, 16));
                v = fmaxf(v, __shfl_xor(v, 32));
                px[j] = v;
            }
            if (pg == 0)
                #pragma unroll
                for (int j = 0; j < 8; j++) pbuf[wv][8 * cg + j] = px[j];
            __builtin_amdgcn_wave_barrier();
            float y1 = bo1v;
            #pragma unroll 4
            for (int kk = 0; kk < 16; kk++) {
                v4f w = ld4(Wo1 + lane * 64 + 4 * kk);
                y1 += w[0] * pbuf[wv][4 * kk] + w[1] * pbuf[wv][4 * kk + 1]
                    + w[2] * pbuf[wv][4 * kk + 2] + w[3] * pbuf[wv][4 * kk + 3];
            }
            y1 = fmaxf(y1, 0.f);
            pbuf[wv][lane] = y1;
            __builtin_amdgcn_wave_barrier();
            float o0 = bo2a, o1 = bo2b;
            #pragma unroll 4
            for (int kk = 0; kk < 16; kk++) {
                v4f w0 = ld4(Wo2 + lane * 64 + 4 * kk);
                v4f w1 = ld4(Wo2 + (64 + lane) * 64 + 4 * kk);
                float p0 = pbuf[wv][4 * kk], p1 = pbuf[wv][4 * kk + 1];
                float p2 = pbuf[wv][4 * kk + 2], p3 = pbuf[wv][4 * kk + 3];
                o0 += w0[0] * p0 + w0[1] * p1 + w0[2] * p2 + w0[3] * p3;
                o1 += w1[0] * p0 + w1[1] * p1 + w1[2] * p2 + w1[3] * p3;
            }
            float vf = __ballot(mv > 0.5f) ? 1.f : 0.f;
            out[(size_t)bn * 128 + lane] = o0 * vf;
            out[(size_t)bn * 128 + 64 + lane] = o1 * vf;
        }
        __builtin_amdgcn_wave_barrier();
    }
    if constexpr (!DO_OUT)
        stats_flush(sp, ssp, red_s, red_ss, S, 256, t, wv, pg, cg);
}

extern "C" void kernel_launch(void* const* d_in, const int* in_sizes, int n_in,
                              void* d_out, int out_size, void* d_ws, size_t ws_size,
                              hipStream_t stream) {
    const float* poly = (const float*)d_in[0];
    const int*   mask = (const int*)d_in[1];
    const float* Wpre = (const float*)d_in[2];
    const float* gpre = (const float*)d_in[3];
    const float* bpre = (const float*)d_in[4];
    const float* W1   = (const float*)d_in[5];
    const float* g1   = (const float*)d_in[6];
    const float* b1   = (const float*)d_in[7];
    const float* W2   = (const float*)d_in[8];
    const float* g2   = (const float*)d_in[9];
    const float* b2   = (const float*)d_in[10];
    const float* Wo1  = (const float*)d_in[11];
    const float* bo1  = (const float*)d_in[12];
    const float* Wo2  = (const float*)d_in[13];
    const float* bo2  = (const float*)d_in[14];

    float* S = (float*)d_ws;
    u16* H16 = (u16*)((char*)d_ws + 8192);
    float* out = (float*)d_out;

    const size_t needWS = 8192 + (size_t)BN_TOT * 2048 * sizeof(u16);  // ~100.7 MB

    hipMemsetAsync(S, 0, 512 * sizeof(float), stream);
    k_mom<<<NBLK, 256, 0, stream>>>(poly, mask, S);
    if (ws_size >= needWS) {
        k_stats2_mfma<<<NBLK, 256, 0, stream>>>(poly, mask, Wpre, gpre, bpre, W1, S, H16);
        k_stats3_mfma<<<NBLK, 256, 0, stream>>>(mask, g1, b1, W2, S, H16);
        k_out_load<<<NBLK, 256, 0, stream>>>(mask, g2, b2, Wo1, bo1, Wo2, bo2, S, H16, out);
    } else {
        k_finalize_mom<<<1, 64, 0, stream>>>(Wpre, gpre, bpre, S);
        k_stats2_fb<<<NBLK, 256, 0, stream>>>(poly, mask, Wpre, W1, S);
        k_finalize<<<1, 64, 0, stream>>>(g1, b1, S, 1);
        k_rec34<false><<<NBLK, 256, 0, stream>>>(poly, mask, Wpre, W1, W2, Wo1, bo1, Wo2, bo2, S, out);
        k_finalize<<<1, 64, 0, stream>>>(g2, b2, S, 2);
        k_rec34<true><<<NBLK, 256, 0, stream>>>(poly, mask, Wpre, W1, W2, Wo1, bo1, Wo2, bo2, S, out);
    }
}

// Round 15
// 415.205 us; speedup vs baseline: 1.1943x; 1.1943x over previous
//
#include <hip/hip_runtime.h>

#define BN_TOT 24576   // B*N
#define NPTS 786432    // BN_TOT*32
#define EPS_ 1e-5f
#define NBLK 2048
#define TOTW (NBLK * 4)   // 8192 waves; 3 polylines per wave exact

typedef float v4f __attribute__((ext_vector_type(4)));
typedef __attribute__((ext_vector_type(8))) short sv8;    // 8 bf16 (4 VGPRs)
typedef __attribute__((ext_vector_type(4))) float fv4;    // MFMA acc
typedef unsigned short u16;
typedef unsigned int u32;

__device__ __forceinline__ v4f ld4(const float* p) { return *(const v4f*)p; }
__device__ __forceinline__ void st4(float* p, v4f v) { *(v4f*)p = v; }

__device__ __forceinline__ float bf2f(u16 u) {
    union { u32 i; float f; } v; v.i = ((u32)u) << 16; return v.f;
}
__device__ __forceinline__ u32 pack2bf(float a, float b) {   // lo=a, hi=b, RNE
    union { float f; u32 i; } x, y; x.f = a; y.f = b;
    u32 xr = x.i + 0x7FFFu + ((x.i >> 16) & 1u);
    u32 yr = y.i + 0x7FFFu + ((y.i >> 16) & 1u);
    return (xr >> 16) | (yr & 0xFFFF0000u);
}

// Workspace S (floats):
// [128..191] sum2 [192..255] sumsq2 [256..319] sum3 [320..383] sumsq3 [384] cnt (fallback)
// [400..444] M (x xT upper-tri 45) [445..453] sum_x (9) [454] cnt_raw
// [512+L*128 ..] scaleL/shiftL (fallback path only)
// H16 at byte offset 8192, ~100.7 MB, TILE-MAJOR (R10-proven):
//   u16 idx(p,ch) = (p&3)*512 + (p>>2)*64 + ch

__global__ void k_finalize(const float* __restrict__ g, const float* __restrict__ b,
                           float* __restrict__ S, int layer) {
    int c = threadIdx.x;
    if (c < 64) {
        float cnt = fmaxf(S[384], 1.f);
        float mean = S[layer * 128 + c] / cnt;
        float var = fmaxf(S[layer * 128 + 64 + c] / cnt - mean * mean, 0.f);
        float sc = g[c] * rsqrtf(var + EPS_);
        float sh = b[c] - mean * sc;
        S[512 + layer * 128 + c] = sc;
        S[512 + layer * 128 + 64 + c] = sh;
    }
}

// ---- moment-based stage-1 stats (R13-proven) -------------------------------
__global__ __launch_bounds__(256) void k_mom(const float* __restrict__ poly,
                                             const int* __restrict__ mask,
                                             float* __restrict__ S) {
    __shared__ float red[4][55];
    const int t = threadIdx.x, wv = t >> 6, lane = t & 63;
    float M[45], sx[9], cc = 0.f;
    #pragma unroll
    for (int i = 0; i < 45; i++) M[i] = 0.f;
    #pragma unroll
    for (int i = 0; i < 9; i++) sx[i] = 0.f;
    for (int idx = blockIdx.x * 256 + t; idx < NPTS; idx += NBLK * 256) {
        float m = (mask[idx] != 0) ? 1.f : 0.f;
        const float* xp = poly + (size_t)idx * 9;
        float x[9];
        #pragma unroll
        for (int j = 0; j < 9; j++) x[j] = xp[j];
        cc += m;
        int k = 0;
        #pragma unroll
        for (int a = 0; a < 9; a++) {
            float xa = x[a] * m;
            sx[a] += xa;
            #pragma unroll
            for (int b2 = a; b2 < 9; b2++) { M[k] += xa * x[b2]; k++; }
        }
    }
    #pragma unroll
    for (int i = 0; i < 45; i++) {
        float v = M[i];
        v += __shfl_xor(v, 1); v += __shfl_xor(v, 2); v += __shfl_xor(v, 4);
        v += __shfl_xor(v, 8); v += __shfl_xor(v, 16); v += __shfl_xor(v, 32);
        M[i] = v;
    }
    #pragma unroll
    for (int i = 0; i < 9; i++) {
        float v = sx[i];
        v += __shfl_xor(v, 1); v += __shfl_xor(v, 2); v += __shfl_xor(v, 4);
        v += __shfl_xor(v, 8); v += __shfl_xor(v, 16); v += __shfl_xor(v, 32);
        sx[i] = v;
    }
    {
        float v = cc;
        v += __shfl_xor(v, 1); v += __shfl_xor(v, 2); v += __shfl_xor(v, 4);
        v += __shfl_xor(v, 8); v += __shfl_xor(v, 16); v += __shfl_xor(v, 32);
        cc = v;
    }
    if (lane == 0) {
        #pragma unroll
        for (int i = 0; i < 45; i++) red[wv][i] = M[i];
        #pragma unroll
        for (int i = 0; i < 9; i++) red[wv][45 + i] = sx[i];
        red[wv][54] = cc;
    }
    __syncthreads();
    if (t < 55) atomicAdd(&S[400 + t], red[0][t] + red[1][t] + red[2][t] + red[3][t]);
}

__global__ void k_finalize_mom(const float* __restrict__ Wpre,
                               const float* __restrict__ g, const float* __restrict__ b,
                               float* __restrict__ S) {
    int c = threadIdx.x;
    if (c < 64) {
        float w[9];
        #pragma unroll
        for (int j = 0; j < 9; j++) w[j] = Wpre[c * 9 + j];
        float cnt = fmaxf(S[454], 1.f);
        float s1 = 0.f;
        #pragma unroll
        for (int j = 0; j < 9; j++) s1 += w[j] * S[445 + j];
        float s2 = 0.f;
        int k = 0;
        #pragma unroll
        for (int a = 0; a < 9; a++)
            #pragma unroll
            for (int b2 = a; b2 < 9; b2++) {
                float mm = S[400 + k];
                s2 += (a == b2) ? w[a] * w[a] * mm : 2.f * w[a] * w[b2] * mm;
                k++;
            }
        float mean = s1 / cnt;
        float var = fmaxf(s2 / cnt - mean * mean, 0.f);
        float sc = g[c] * rsqrtf(var + EPS_);
        float sh = b[c] - mean * sc;
        S[512 + c] = sc;
        S[576 + c] = sh;
        if (c == 0) S[384] = S[454];
    }
}

// ---- shared helpers --------------------------------------------------------
__device__ __forceinline__ void mm_acc(float a[4][8], v4f av, v4f w0, v4f w1) {
    #pragma unroll
    for (int i = 0; i < 4; i++) {
        #pragma unroll
        for (int j = 0; j < 4; j++) {
            a[i][j] += av[i] * w0[j];
            a[i][4 + j] += av[i] * w1[j];
        }
    }
}

__device__ __forceinline__ void tzero(float a[4][8]) {
    #pragma unroll
    for (int i = 0; i < 4; i++)
        #pragma unroll
        for (int j = 0; j < 8; j++) a[i][j] = 0.f;
}

__device__ __forceinline__ void load_x(const float* xg, float* xTw, int lane) {
    for (int e = lane; e < 288; e += 64) {
        float v = xg[e];
        int p = e / 9, c = e - 9 * p;
        xTw[c * 36 + p] = v;
    }
}

__device__ __forceinline__ void stage1(const float* xTw, const float* WpT,
                                       int pg, int cg, float a1[4][8]) {
    tzero(a1);
    #pragma unroll
    for (int k = 0; k < 9; k++) {
        v4f av = ld4(xTw + k * 36 + 4 * pg);
        v4f w0 = ld4(WpT + k * 64 + 8 * cg);
        v4f w1 = ld4(WpT + k * 64 + 8 * cg + 4);
        mm_acc(a1, av, w0, w1);
    }
}

__device__ __forceinline__ void gemv64(const float* actw, const float* WT,
                                       int pg, int cg, float a[4][8]) {
    #pragma unroll 8
    for (int k = 0; k < 64; k++) {
        v4f av = ld4(actw + k * 32 + 4 * (pg ^ (k >> 3)));
        v4f w0 = ld4(WT + k * 64 + 8 * cg);
        v4f w1 = ld4(WT + k * 64 + 8 * cg + 4);
        mm_acc(a, av, w0, w1);
    }
}

__device__ __forceinline__ void bn_store_act(float* actw, const float a[4][8],
                                             const float* sc, const float* sh,
                                             const float m[4], int pg, int cg,
                                             float f[4][8]) {
    #pragma unroll
    for (int j = 0; j < 8; j++) {
        v4f v;
        #pragma unroll
        for (int i = 0; i < 4; i++) {
            float x = fmaxf(a[i][j] * sc[j] + sh[j], 0.f) * m[i];
            v[i] = x; f[i][j] = x;
        }
        st4(actw + (8 * cg + j) * 32 + 4 * (pg ^ cg), v);
    }
}

__device__ __forceinline__ void pool_reduce(const float f[4][8], float pmax[8]) {
    #pragma unroll
    for (int j = 0; j < 8; j++) {
        float v = fmaxf(fmaxf(f[0][j], f[1][j]), fmaxf(f[2][j], f[3][j]));
        v = fmaxf(v, __shfl_xor(v, 8));
        v = fmaxf(v, __shfl_xor(v, 16));
        v = fmaxf(v, __shfl_xor(v, 32));
        pmax[j] = v;
    }
}

__device__ __forceinline__ void qa_glob(const float pmax[8], const float* W1,
                                        float* pbufw, int pg, int cg, float qa[8]) {
    if (pg == 0)
        #pragma unroll
        for (int j = 0; j < 8; j++) pbufw[8 * cg + j] = pmax[j];
    __builtin_amdgcn_wave_barrier();
    #pragma unroll
    for (int j = 0; j < 8; j++) qa[j] = 0.f;
    #pragma unroll 4
    for (int kk = 0; kk < 16; kk++) {
        float p0 = pbufw[4 * kk], p1 = pbufw[4 * kk + 1];
        float p2 = pbufw[4 * kk + 2], p3 = pbufw[4 * kk + 3];
        #pragma unroll
        for (int j = 0; j < 8; j++) {
            v4f w = ld4(W1 + (8 * cg + j) * 128 + 64 + 4 * kk);
            qa[j] += w[0] * p0 + w[1] * p1 + w[2] * p2 + w[3] * p3;
        }
    }
}

__device__ __forceinline__ void stats_acc(const float a[4][8], const float m[4],
                                          float sp[8], float ssp[8]) {
    #pragma unroll
    for (int i = 0; i < 4; i++)
        #pragma unroll
        for (int j = 0; j < 8; j++) {
            float hv = a[i][j] * m[i];
            sp[j] += hv; ssp[j] += hv * a[i][j];
        }
}

__device__ __forceinline__ void stats_flush(float sp[8], float ssp[8],
                                            float (*red_s)[64], float (*red_ss)[64],
                                            float* S, int base, int t, int wv,
                                            int pg, int cg) {
    #pragma unroll
    for (int j = 0; j < 8; j++) {
        float v = sp[j];
        v += __shfl_xor(v, 8); v += __shfl_xor(v, 16); v += __shfl_xor(v, 32);
        sp[j] = v;
        float w = ssp[j];
        w += __shfl_xor(w, 8); w += __shfl_xor(w, 16); w += __shfl_xor(w, 32);
        ssp[j] = w;
    }
    if (pg == 0)
        #pragma unroll
        for (int j = 0; j < 8; j++) { red_s[wv][8 * cg + j] = sp[j]; red_ss[wv][8 * cg + j] = ssp[j]; }
    __syncthreads();
    if (t < 64) {
        atomicAdd(&S[base + t], red_s[0][t] + red_s[1][t] + red_s[2][t] + red_s[3][t]);
        atomicAdd(&S[base + 64 + t], red_ss[0][t] + red_ss[1][t] + red_ss[2][t] + red_ss[3][t]);
    }
}

// ---- pass 2 (big ws): R13-proven body + inlined BN1 finalize ---------------
// Stage2 MFMA: A=W1 (K=128), B=[feat;pooled]. Stage1 VALU in B-layout.
// Layouts (HW-validated): A[m=lane&15][k=quad*8+j], B[k=quad*8+j][n=lane&15],
// C: col(n)=lane&15, row(m)=mt*16+quad*4+r.
__global__ __launch_bounds__(256) void k_stats2_mfma(const float* __restrict__ poly,
                                                     const int* __restrict__ mask,
                                                     const float* __restrict__ Wpre,
                                                     const float* __restrict__ gpre,
                                                     const float* __restrict__ bpre,
                                                     const float* __restrict__ W1,
                                                     float* __restrict__ S,
                                                     u16* __restrict__ H16) {
    __shared__ __align__(16) float WpT[576];
    __shared__ __align__(16) float xT[4][324];
    __shared__ u16 h1b[4][32 * 68];
    __shared__ float scsh[128];
    __shared__ float red_s[4][64], red_ss[4][64];
    const int t = threadIdx.x, wv = t >> 6, lane = t & 63;
    const int n = lane & 15, quad = lane >> 4;
    for (int i = t; i < 576; i += 256) { int c = i >> 6, ch = i & 63; WpT[i] = Wpre[ch * 9 + c]; }

    // inline BN1 finalize from moments (cold preamble)
    if (t < 64) {
        float w[9];
        #pragma unroll
        for (int j = 0; j < 9; j++) w[j] = Wpre[t * 9 + j];
        float cnt = fmaxf(S[454], 1.f);
        float s1 = 0.f;
        #pragma unroll
        for (int j = 0; j < 9; j++) s1 += w[j] * S[445 + j];
        float s2 = 0.f;
        int k = 0;
        #pragma unroll
        for (int a = 0; a < 9; a++)
            #pragma unroll
            for (int b2 = a; b2 < 9; b2++) {
                float mm = S[400 + k];
                s2 += (a == b2) ? w[a] * w[a] * mm : 2.f * w[a] * w[b2] * mm;
                k++;
            }
        float mean = s1 / cnt;
        float var = fmaxf(s2 / cnt - mean * mean, 0.f);
        float sc = gpre[t] * rsqrtf(var + EPS_);
        scsh[t] = sc;
        scsh[64 + t] = bpre[t] - mean * sc;
    }

    sv8 aw[4][4];
    #pragma unroll
    for (int mt = 0; mt < 4; mt++)
        #pragma unroll
        for (int ss = 0; ss < 4; ss++) {
            const float* wr = W1 + (size_t)(mt * 16 + n) * 128 + ss * 32 + quad * 8;
            union { sv8 v; u32 w[4]; } uu;
            #pragma unroll
            for (int d = 0; d < 4; d++) uu.w[d] = pack2bf(wr[2 * d], wr[2 * d + 1]);
            aw[mt][ss] = uu.v;
        }
    __syncthreads();
    float sck[16], shk[16];
    #pragma unroll
    for (int s = 0; s < 2; s++)
        #pragma unroll
        for (int j = 0; j < 8; j++) {
            int c = s * 32 + quad * 8 + j;
            sck[s * 8 + j] = scsh[c];
            shk[s * 8 + j] = scsh[64 + c];
        }

    float sp16[16], ssp16[16];
    #pragma unroll
    for (int e = 0; e < 16; e++) { sp16[e] = 0.f; ssp16[e] = 0.f; }

    const int wgid = blockIdx.x * 4 + wv;
    for (int bn = wgid; bn < BN_TOT; bn += TOTW) {
        float mv = (lane < 32 && mask[bn * 32 + lane] != 0) ? 1.f : 0.f;
        load_x(poly + (size_t)bn * 288, xT[wv], lane);
        __builtin_amdgcn_wave_barrier();
        // stage1 (VALU) for points {n, 16+n}, channels {s*32+quad*8+j}
        float f0[16], f1[16];
        #pragma unroll
        for (int e = 0; e < 16; e++) { f0[e] = 0.f; f1[e] = 0.f; }
        #pragma unroll
        for (int k = 0; k < 9; k++) {
            float x0 = xT[wv][k * 36 + n];
            float x1 = xT[wv][k * 36 + 16 + n];
            v4f wA0 = ld4(WpT + k * 64 + quad * 8);
            v4f wA1 = ld4(WpT + k * 64 + quad * 8 + 4);
            v4f wB0 = ld4(WpT + k * 64 + 32 + quad * 8);
            v4f wB1 = ld4(WpT + k * 64 + 32 + quad * 8 + 4);
            #pragma unroll
            for (int j = 0; j < 4; j++) {
                f0[j] += x0 * wA0[j];  f0[4 + j] += x0 * wA1[j];
                f0[8 + j] += x0 * wB0[j]; f0[12 + j] += x0 * wB1[j];
                f1[j] += x1 * wA0[j];  f1[4 + j] += x1 * wA1[j];
                f1[8 + j] += x1 * wB0[j]; f1[12 + j] += x1 * wB1[j];
            }
        }
        float mp0 = __shfl(mv, n), mp1 = __shfl(mv, 16 + n);
        #pragma unroll
        for (int e = 0; e < 16; e++) {
            f0[e] = fmaxf(f0[e] * sck[e] + shk[e], 0.f) * mp0;
            f1[e] = fmaxf(f1[e] * sck[e] + shk[e], 0.f) * mp1;
        }
        float pm[16];
        #pragma unroll
        for (int e = 0; e < 16; e++) {
            float v = fmaxf(f0[e], f1[e]);
            v = fmaxf(v, __shfl_xor(v, 1));
            v = fmaxf(v, __shfl_xor(v, 2));
            v = fmaxf(v, __shfl_xor(v, 4));
            v = fmaxf(v, __shfl_xor(v, 8));
            pm[e] = v;
        }
        sv8 bg0[2], bg1[2], bp[2];
        #pragma unroll
        for (int s = 0; s < 2; s++) {
            union { sv8 v; u32 w[4]; } a, b, c;
            #pragma unroll
            for (int d = 0; d < 4; d++) {
                a.w[d] = pack2bf(f0[s * 8 + 2 * d], f0[s * 8 + 2 * d + 1]);
                b.w[d] = pack2bf(f1[s * 8 + 2 * d], f1[s * 8 + 2 * d + 1]);
                c.w[d] = pack2bf(pm[s * 8 + 2 * d], pm[s * 8 + 2 * d + 1]);
            }
            bg0[s] = a.v; bg1[s] = b.v; bp[s] = c.v;
        }
        fv4 acc[4][2];
        #pragma unroll
        for (int mt = 0; mt < 4; mt++) {
            #pragma unroll
            for (int nt = 0; nt < 2; nt++) { acc[mt][nt][0] = 0.f; acc[mt][nt][1] = 0.f; acc[mt][nt][2] = 0.f; acc[mt][nt][3] = 0.f; }
            acc[mt][0] = __builtin_amdgcn_mfma_f32_16x16x32_bf16(aw[mt][0], bg0[0], acc[mt][0], 0, 0, 0);
            acc[mt][0] = __builtin_amdgcn_mfma_f32_16x16x32_bf16(aw[mt][1], bg0[1], acc[mt][0], 0, 0, 0);
            acc[mt][0] = __builtin_amdgcn_mfma_f32_16x16x32_bf16(aw[mt][2], bp[0], acc[mt][0], 0, 0, 0);
            acc[mt][0] = __builtin_amdgcn_mfma_f32_16x16x32_bf16(aw[mt][3], bp[1], acc[mt][0], 0, 0, 0);
            acc[mt][1] = __builtin_amdgcn_mfma_f32_16x16x32_bf16(aw[mt][0], bg1[0], acc[mt][1], 0, 0, 0);
            acc[mt][1] = __builtin_amdgcn_mfma_f32_16x16x32_bf16(aw[mt][1], bg1[1], acc[mt][1], 0, 0, 0);
            acc[mt][1] = __builtin_amdgcn_mfma_f32_16x16x32_bf16(aw[mt][2], bp[0], acc[mt][1], 0, 0, 0);
            acc[mt][1] = __builtin_amdgcn_mfma_f32_16x16x32_bf16(aw[mt][3], bp[1], acc[mt][1], 0, 0, 0);
        }
        float mpn[2] = {mp0, mp1};
        #pragma unroll
        for (int nt = 0; nt < 2; nt++) {
            int p = nt * 16 + n;
            float mp = mpn[nt];
            #pragma unroll
            for (int mt = 0; mt < 4; mt++) {
                #pragma unroll
                for (int r = 0; r < 4; r++) {
                    float hv = acc[mt][nt][r];
                    sp16[mt * 4 + r] += hv * mp;
                    ssp16[mt * 4 + r] += hv * hv * mp;
                }
                uint2 pk;
                pk.x = pack2bf(acc[mt][nt][0], acc[mt][nt][1]);
                pk.y = pack2bf(acc[mt][nt][2], acc[mt][nt][3]);
                *(uint2*)&h1b[wv][p * 68 + mt * 16 + quad * 4] = pk;
            }
        }
        __builtin_amdgcn_wave_barrier();
        u16* Hw = H16 + (size_t)bn * 2048;
        #pragma unroll
        for (int i = 0; i < 4; i++) {
            int p = 4 * (lane >> 3) + i;
            int chb = 8 * (lane & 7);
            uint4 v = *(const uint4*)&h1b[wv][p * 68 + chb];
            *(uint4*)(Hw + i * 512 + lane * 8) = v;
        }
        __builtin_amdgcn_wave_barrier();
    }
    #pragma unroll
    for (int e = 0; e < 16; e++) {
        float v = sp16[e];
        v += __shfl_xor(v, 1); v += __shfl_xor(v, 2); v += __shfl_xor(v, 4); v += __shfl_xor(v, 8);
        sp16[e] = v;
        float w = ssp16[e];
        w += __shfl_xor(w, 1); w += __shfl_xor(w, 2); w += __shfl_xor(w, 4); w += __shfl_xor(w, 8);
        ssp16[e] = w;
    }
    if (n == 0) {
        #pragma unroll
        for (int mt = 0; mt < 4; mt++)
            #pragma unroll
            for (int r = 0; r < 4; r++) {
                red_s[wv][mt * 16 + quad * 4 + r] = sp16[mt * 4 + r];
                red_ss[wv][mt * 16 + quad * 4 + r] = ssp16[mt * 4 + r];
            }
    }
    __syncthreads();
    if (t < 64) {
        atomicAdd(&S[128 + t], red_s[0][t] + red_s[1][t] + red_s[2][t] + red_s[3][t]);
        atomicAdd(&S[128 + 64 + t], red_ss[0][t] + red_ss[1][t] + red_ss[2][t] + red_ss[3][t]);
    }
}

// ---- pass 3 (big ws): R11-proven body + inlined BN2 finalize ---------------
__global__ __launch_bounds__(256) void k_stats3_mfma(const int* __restrict__ mask,
                                                     const float* __restrict__ g1,
                                                     const float* __restrict__ b1,
                                                     const float* __restrict__ W2,
                                                     float* __restrict__ S,
                                                     u16* __restrict__ H16) {
    __shared__ u16 h2b[4][32 * 68];
    __shared__ float scsh[128];
    __shared__ float red_s[4][64], red_ss[4][64];
    const int t = threadIdx.x, wv = t >> 6, lane = t & 63;
    const int n = lane & 15, quad = lane >> 4;

    if (t < 64) {
        float cnt = fmaxf(S[454], 1.f);
        float mean = S[128 + t] / cnt;
        float var = fmaxf(S[192 + t] / cnt - mean * mean, 0.f);
        float sc = g1[t] * rsqrtf(var + EPS_);
        scsh[t] = sc;
        scsh[64 + t] = b1[t] - mean * sc;
    }

    sv8 aw[4][2];
    #pragma unroll
    for (int mt = 0; mt < 4; mt++)
        #pragma unroll
        for (int s = 0; s < 2; s++) {
            const float* wr = W2 + (mt * 16 + n) * 64 + s * 32 + quad * 8;
            union { sv8 v; u32 w[4]; } uu;
            #pragma unroll
            for (int d = 0; d < 4; d++) uu.w[d] = pack2bf(wr[2 * d], wr[2 * d + 1]);
            aw[mt][s] = uu.v;
        }
    __syncthreads();
    float sck[16], shk[16];
    #pragma unroll
    for (int s = 0; s < 2; s++)
        #pragma unroll
        for (int j = 0; j < 8; j++) {
            int k = s * 32 + quad * 8 + j;
            sck[s * 8 + j] = scsh[k];
            shk[s * 8 + j] = scsh[64 + k];
        }

    float sp16[16], ssp16[16];
    #pragma unroll
    for (int e = 0; e < 16; e++) { sp16[e] = 0.f; ssp16[e] = 0.f; }

    const int wgid = blockIdx.x * 4 + wv;
    for (int bn = wgid; bn < BN_TOT; bn += TOTW) {
        float mv = (lane < 32 && mask[bn * 32 + lane] != 0) ? 1.f : 0.f;
        const u16* Hb = H16 + (size_t)bn * 2048;
        fv4 acc[4][2];
        #pragma unroll
        for (int mt = 0; mt < 4; mt++)
            #pragma unroll
            for (int nt = 0; nt < 2; nt++) { acc[mt][nt][0] = 0.f; acc[mt][nt][1] = 0.f; acc[mt][nt][2] = 0.f; acc[mt][nt][3] = 0.f; }
        float mpn[2];
        #pragma unroll
        for (int nt = 0; nt < 2; nt++) {
            int p = nt * 16 + n;
            float mp = __shfl(mv, p);
            mpn[nt] = mp;
            sv8 bg[2];
            #pragma unroll
            for (int s = 0; s < 2; s++) {
                int base = (p & 3) * 512 + (p >> 2) * 64 + s * 32 + quad * 8;
                uint4 hw = *(const uint4*)(Hb + base);
                u32 ws[4] = {hw.x, hw.y, hw.z, hw.w};
                union { sv8 v; u32 w[4]; } uu;
                #pragma unroll
                for (int d = 0; d < 4; d++) {
                    union { u32 u; float f; } lo, hi;
                    lo.u = ws[d] << 16; hi.u = ws[d] & 0xFFFF0000u;
                    float g0 = fmaxf(lo.f * sck[s * 8 + 2 * d] + shk[s * 8 + 2 * d], 0.f) * mp;
                    float g1v = fmaxf(hi.f * sck[s * 8 + 2 * d + 1] + shk[s * 8 + 2 * d + 1], 0.f) * mp;
                    uu.w[d] = pack2bf(g0, g1v);
                }
                bg[s] = uu.v;
            }
            #pragma unroll
            for (int mt = 0; mt < 4; mt++) {
                acc[mt][nt] = __builtin_amdgcn_mfma_f32_16x16x32_bf16(aw[mt][0], bg[0], acc[mt][nt], 0, 0, 0);
                acc[mt][nt] = __builtin_amdgcn_mfma_f32_16x16x32_bf16(aw[mt][1], bg[1], acc[mt][nt], 0, 0, 0);
            }
        }
        #pragma unroll
        for (int nt = 0; nt < 2; nt++) {
            int p = nt * 16 + n;
            float mp = mpn[nt];
            #pragma unroll
            for (int mt = 0; mt < 4; mt++) {
                #pragma unroll
                for (int r = 0; r < 4; r++) {
                    float hv = acc[mt][nt][r];
                    sp16[mt * 4 + r] += hv * mp;
                    ssp16[mt * 4 + r] += hv * hv * mp;
                }
                uint2 pk;
                pk.x = pack2bf(acc[mt][nt][0], acc[mt][nt][1]);
                pk.y = pack2bf(acc[mt][nt][2], acc[mt][nt][3]);
                *(uint2*)&h2b[wv][p * 68 + mt * 16 + quad * 4] = pk;
            }
        }
        __builtin_amdgcn_wave_barrier();
        u16* Hw = H16 + (size_t)bn * 2048;
        #pragma unroll
        for (int i = 0; i < 4; i++) {
            int p = 4 * (lane >> 3) + i;
            int chb = 8 * (lane & 7);
            uint4 v = *(const uint4*)&h2b[wv][p * 68 + chb];
            *(uint4*)(Hw + i * 512 + lane * 8) = v;
        }
        __builtin_amdgcn_wave_barrier();
    }
    #pragma unroll
    for (int e = 0; e < 16; e++) {
        float v = sp16[e];
        v += __shfl_xor(v, 1); v += __shfl_xor(v, 2); v += __shfl_xor(v, 4); v += __shfl_xor(v, 8);
        sp16[e] = v;
        float w = ssp16[e];
        w += __shfl_xor(w, 1); w += __shfl_xor(w, 2); w += __shfl_xor(w, 4); w += __shfl_xor(w, 8);
        ssp16[e] = w;
    }
    if (n == 0) {
        #pragma unroll
        for (int mt = 0; mt < 4; mt++)
            #pragma unroll
            for (int r = 0; r < 4; r++) {
                red_s[wv][mt * 16 + quad * 4 + r] = sp16[mt * 4 + r];
                red_ss[wv][mt * 16 + quad * 4 + r] = ssp16[mt * 4 + r];
            }
    }
    __syncthreads();
    if (t < 64) {
        atomicAdd(&S[256 + t], red_s[0][t] + red_s[1][t] + red_s[2][t] + red_s[3][t]);
        atomicAdd(&S[256 + 64 + t], red_ss[0][t] + red_ss[1][t] + red_ss[2][t] + red_ss[3][t]);
    }
}

// ---- pass 4 (big ws): R10-proven body + inlined BN3 finalize ---------------
__global__ __launch_bounds__(256) void k_out_load(const int* __restrict__ mask,
                                                  const float* __restrict__ g2,
                                                  const float* __restrict__ b2,
                                                  const float* __restrict__ Wo1,
                                                  const float* __restrict__ bo1,
                                                  const float* __restrict__ Wo2,
                                                  const float* __restrict__ bo2,
                                                  const float* __restrict__ S,
                                                  const u16* __restrict__ H16,
                                                  float* __restrict__ out) {
    __shared__ __align__(16) float Wo1T[4096];
    __shared__ __align__(16) float Wo2T[8192];
    __shared__ float pbuf[4][64];
    __shared__ float scsh[128];
    const int t = threadIdx.x, wv = t >> 6, lane = t & 63;
    if (t < 64) {
        float cnt = fmaxf(S[454], 1.f);
        float mean = S[256 + t] / cnt;
        float var = fmaxf(S[320 + t] / cnt - mean * mean, 0.f);
        float sc = g2[t] * rsqrtf(var + EPS_);
        scsh[t] = sc;
        scsh[64 + t] = b2[t] - mean * sc;
    }
    for (int i = t; i < 4096; i += 256) { int k = i >> 6, ch = i & 63; Wo1T[i] = Wo1[ch * 64 + k]; }
    for (int i = t; i < 8192; i += 256) { int k = i >> 7, o = i & 127; Wo2T[i] = Wo2[o * 64 + k]; }
    __syncthreads();
    float sc3 = scsh[lane], sh3 = scsh[64 + lane];
    float bo1v = bo1[lane], bo2a = bo2[lane], bo2b = bo2[64 + lane];
    const int wgid = blockIdx.x * 4 + wv;
    for (int bn = wgid; bn < BN_TOT; bn += TOTW) {
        float mv = (lane < 32 && mask[bn * 32 + lane] != 0) ? 1.f : 0.f;
        float vf = __ballot(mv > 0.5f) ? 1.f : 0.f;
        const u16* Hb16 = H16 + (size_t)bn * 2048;
        float mx = 0.f;
        #pragma unroll
        for (int i = 0; i < 4; i++)
            #pragma unroll
            for (int pgx = 0; pgx < 8; pgx++) {
                float h = bf2f(Hb16[i * 512 + pgx * 64 + lane]);
                float mp = __shfl(mv, 4 * pgx + i);
                mx = fmaxf(mx, fmaxf(h * sc3 + sh3, 0.f) * mp);
            }
        pbuf[wv][lane] = mx;
        __builtin_amdgcn_wave_barrier();
        float y1 = bo1v;
        #pragma unroll 8
        for (int k = 0; k < 64; k++) y1 += Wo1T[k * 64 + lane] * pbuf[wv][k];
        y1 = fmaxf(y1, 0.f);
        pbuf[wv][lane] = y1;
        __builtin_amdgcn_wave_barrier();
        float o0 = bo2a, o1 = bo2b;
        #pragma unroll 8
        for (int k = 0; k < 64; k++) {
            float yv = pbuf[wv][k];
            o0 += Wo2T[k * 128 + lane] * yv;
            o1 += Wo2T[k * 128 + 64 + lane] * yv;
        }
        out[(size_t)bn * 128 + lane] = o0 * vf;
        out[(size_t)bn * 128 + 64 + lane] = o1 * vf;
        __builtin_amdgcn_wave_barrier();
    }
}

// ---- fallback (small ws): recompute path, untouched ------------------------
__device__ __forceinline__ void qa_lds_fb(const float pmax[8], const float* W1pT,
                                          int cg, float qa[8]) {
    #pragma unroll
    for (int j = 0; j < 8; j++) qa[j] = 0.f;
    #pragma unroll
    for (int k = 0; k < 64; k++) {
        float pv = __shfl(pmax[k & 7], k >> 3);
        v4f w0 = ld4(W1pT + k * 64 + 8 * cg);
        v4f w1 = ld4(W1pT + k * 64 + 8 * cg + 4);
        #pragma unroll
        for (int j = 0; j < 4; j++) { qa[j] += pv * w0[j]; qa[4 + j] += pv * w1[j]; }
    }
}

__global__ __launch_bounds__(256) void k_stats2_fb(const float* __restrict__ poly,
                                                   const int* __restrict__ mask,
                                                   const float* __restrict__ Wpre,
                                                   const float* __restrict__ W1,
                                                   float* __restrict__ S) {
    __shared__ __align__(16) float WpT[576];
    __shared__ __align__(16) float W1aT[4096];
    __shared__ __align__(16) float W1pT[4096];
    __shared__ __align__(16) float act[4][2048];
    __shared__ __align__(16) float xT[4][324];
    __shared__ float red_s[4][64], red_ss[4][64];
    const int t = threadIdx.x, wv = t >> 6, lane = t & 63;
    const int pg = lane >> 3, cg = lane & 7;
    for (int i = t; i < 576; i += 256) { int c = i >> 6, ch = i & 63; WpT[i] = Wpre[ch * 9 + c]; }
    for (int i = t; i < 4096; i += 256) {
        int k = i >> 6, ch = i & 63;
        W1aT[i] = W1[ch * 128 + k];
        W1pT[i] = W1[ch * 128 + 64 + k];
    }
    __syncthreads();
    float sc1[8], sh1[8];
    #pragma unroll
    for (int j = 0; j < 8; j++) { sc1[j] = S[512 + 8 * cg + j]; sh1[j] = S[576 + 8 * cg + j]; }
    float sp[8] = {0}, ssp[8] = {0};
    const int wgid = blockIdx.x * 4 + wv;
    for (int bn = wgid; bn < BN_TOT; bn += TOTW) {
        float mv = (lane < 32 && mask[bn * 32 + lane] != 0) ? 1.f : 0.f;
        float m[4];
        #pragma unroll
        for (int i = 0; i < 4; i++) m[i] = __shfl(mv, 4 * pg + i);
        load_x(poly + (size_t)bn * 288, xT[wv], lane);
        __builtin_amdgcn_wave_barrier();
        float a1[4][8], f[4][8];
        stage1(xT[wv], WpT, pg, cg, a1);
        bn_store_act(act[wv], a1, sc1, sh1, m, pg, cg, f);
        float pmax[8], qa[8];
        pool_reduce(f, pmax);
        qa_lds_fb(pmax, W1pT, cg, qa);
        __builtin_amdgcn_wave_barrier();
        float a2[4][8];
        #pragma unroll
        for (int i = 0; i < 4; i++)
            #pragma unroll
            for (int j = 0; j < 8; j++) a2[i][j] = qa[j];
        gemv64(act[wv], W1aT, pg, cg, a2);
        stats_acc(a2, m, sp, ssp);
        __builtin_amdgcn_wave_barrier();
    }
    stats_flush(sp, ssp, red_s, red_ss, S, 128, t, wv, pg, cg);
}

template<bool DO_OUT>
__global__ __launch_bounds__(256) void k_rec34(const float* __restrict__ poly,
                                               const int* __restrict__ mask,
                                               const float* __restrict__ Wpre,
                                               const float* __restrict__ W1,
                                               const float* __restrict__ W2,
                                               const float* __restrict__ Wo1,
                                               const float* __restrict__ bo1,
                                               const float* __restrict__ Wo2,
                                               const float* __restrict__ bo2,
                                               float* __restrict__ S,
                                               float* __restrict__ out) {
    __shared__ __align__(16) float WpT[576];
    __shared__ __align__(16) float W1aT[4096];
    __shared__ __align__(16) float W2T[4096];
    __shared__ __align__(16) float act[4][2048];
    __shared__ __align__(16) float xT[4][324];
    __shared__ float pbuf[4][64];
    __shared__ float red_s[4][64], red_ss[4][64];
    const int t = threadIdx.x, wv = t >> 6, lane = t & 63;
    const int pg = lane >> 3, cg = lane & 7;
    for (int i = t; i < 576; i += 256) { int c = i >> 6, ch = i & 63; WpT[i] = Wpre[ch * 9 + c]; }
    for (int i = t; i < 4096; i += 256) {
        int k = i >> 6, ch = i & 63;
        W1aT[i] = W1[ch * 128 + k];
        W2T[i] = W2[ch * 64 + k];
    }
    __syncthreads();
    float sc1[8], sh1[8], sc2[8], sh2[8], sc3[8], sh3[8];
    #pragma unroll
    for (int j = 0; j < 8; j++) {
        sc1[j] = S[512 + 8 * cg + j]; sh1[j] = S[576 + 8 * cg + j];
        sc2[j] = S[640 + 8 * cg + j]; sh2[j] = S[704 + 8 * cg + j];
    }
    if constexpr (DO_OUT)
        #pragma unroll
        for (int j = 0; j < 8; j++) { sc3[j] = S[768 + 8 * cg + j]; sh3[j] = S[832 + 8 * cg + j]; }
    float bo1v = 0.f, bo2a = 0.f, bo2b = 0.f;
    if constexpr (DO_OUT) { bo1v = bo1[lane]; bo2a = bo2[lane]; bo2b = bo2[64 + lane]; }
    float sp[8] = {0}, ssp[8] = {0};
    const int wgid = blockIdx.x * 4 + wv;
    for (int bn = wgid; bn < BN_TOT; bn += TOTW) {
        float mv = (lane < 32 && mask[bn * 32 + lane] != 0) ? 1.f : 0.f;
        float m[4];
        #pragma unroll
        for (int i = 0; i < 4; i++) m[i] = __shfl(mv, 4 * pg + i);
        load_x(poly + (size_t)bn * 288, xT[wv], lane);
        __builtin_amdgcn_wave_barrier();
        float a1[4][8], f[4][8];
        stage1(xT[wv], WpT, pg, cg, a1);
        bn_store_act(act[wv], a1, sc1, sh1, m, pg, cg, f);
        float pmax[8], qa[8];
        pool_reduce(f, pmax);
        qa_glob(pmax, W1, pbuf[wv], pg, cg, qa);
        __builtin_amdgcn_wave_barrier();
        float a2[4][8];
        #pragma unroll
        for (int i = 0; i < 4; i++)
            #pragma unroll
            for (int j = 0; j < 8; j++) a2[i][j] = qa[j];
        gemv64(act[wv], W1aT, pg, cg, a2);
        __builtin_amdgcn_wave_barrier();
        bn_store_act(act[wv], a2, sc2, sh2, m, pg, cg, f);
        __builtin_amdgcn_wave_barrier();
        float a3[4][8];
        tzero(a3);
        gemv64(act[wv], W2T, pg, cg, a3);
        if constexpr (!DO_OUT) {
            stats_acc(a3, m, sp, ssp);
        } else {
            float px[8];
            #pragma unroll
            for (int j = 0; j < 8; j++) {
                float v = 0.f;
                #pragma unroll
                for (int i = 0; i < 4; i++)
                    v = fmaxf(v, fmaxf(a3[i][j] * sc3[j] + sh3[j], 0.f) * m[i]);
                px[j] = v;
            }
            #pragma unroll
            for (int j = 0; j < 8; j++) {
                float v = px[j];
                v = fmaxf(v, __shfl_xor(v, 8));
                v = fmaxf(v, __shfl_xor(v, 16));
                v = fmaxf(v, __shfl_xor(v, 32));
                px[j] = v;
            }
            if (pg == 0)
                #pragma unroll
                for (int j = 0; j < 8; j++) pbuf[wv][8 * cg + j] = px[j];
            __builtin_amdgcn_wave_barrier();
            float y1 = bo1v;
            #pragma unroll 4
            for (int kk = 0; kk < 16; kk++) {
                v4f w = ld4(Wo1 + lane * 64 + 4 * kk);
                y1 += w[0] * pbuf[wv][4 * kk] + w[1] * pbuf[wv][4 * kk + 1]
                    + w[2] * pbuf[wv][4 * kk + 2] + w[3] * pbuf[wv][4 * kk + 3];
            }
            y1 = fmaxf(y1, 0.f);
            pbuf[wv][lane] = y1;
            __builtin_amdgcn_wave_barrier();
            float o0 = bo2a, o1 = bo2b;
            #pragma unroll 4
            for (int kk = 0; kk < 16; kk++) {
                v4f w0 = ld4(Wo2 + lane * 64 + 4 * kk);
                v4f w1 = ld4(Wo2 + (64 + lane) * 64 + 4 * kk);
                float p0 = pbuf[wv][4 * kk], p1 = pbuf[wv][4 * kk + 1];
                float p2 = pbuf[wv][4 * kk + 2], p3 = pbuf[wv][4 * kk + 3];
                o0 += w0[0] * p0 + w0[1] * p1 + w0[2] * p2 + w0[3] * p3;
                o1 += w1[0] * p0 + w1[1] * p1 + w1[2] * p2 + w1[3] * p3;
            }
            float vf = __ballot(mv > 0.5f) ? 1.f : 0.f;
            out[(size_t)bn * 128 + lane] = o0 * vf;
            out[(size_t)bn * 128 + 64 + lane] = o1 * vf;
        }
        __builtin_amdgcn_wave_barrier();
    }
    if constexpr (!DO_OUT)
        stats_flush(sp, ssp, red_s, red_ss, S, 256, t, wv, pg, cg);
}

extern "C" void kernel_launch(void* const* d_in, const int* in_sizes, int n_in,
                              void* d_out, int out_size, void* d_ws, size_t ws_size,
                              hipStream_t stream) {
    const float* poly = (const float*)d_in[0];
    const int*   mask = (const int*)d_in[1];
    const float* Wpre = (const float*)d_in[2];
    const float* gpre = (const float*)d_in[3];
    const float* bpre = (const float*)d_in[4];
    const float* W1   = (const float*)d_in[5];
    const float* g1   = (const float*)d_in[6];
    const float* b1   = (const float*)d_in[7];
    const float* W2   = (const float*)d_in[8];
    const float* g2   = (const float*)d_in[9];
    const float* b2   = (const float*)d_in[10];
    const float* Wo1  = (const float*)d_in[11];
    const float* bo1  = (const float*)d_in[12];
    const float* Wo2  = (const float*)d_in[13];
    const float* bo2  = (const float*)d_in[14];

    float* S = (float*)d_ws;
    u16* H16 = (u16*)((char*)d_ws + 8192);
    float* out = (float*)d_out;

    const size_t needWS = 8192 + (size_t)BN_TOT * 2048 * sizeof(u16);  // ~100.7 MB

    hipMemsetAsync(S, 0, 512 * sizeof(float), stream);
    k_mom<<<NBLK, 256, 0, stream>>>(poly, mask, S);
    if (ws_size >= needWS) {
        k_stats2_mfma<<<NBLK, 256, 0, stream>>>(poly, mask, Wpre, gpre, bpre, W1, S, H16);
        k_stats3_mfma<<<NBLK, 256, 0, stream>>>(mask, g1, b1, W2, S, H16);
        k_out_load<<<NBLK, 256, 0, stream>>>(mask, g2, b2, Wo1, bo1, Wo2, bo2, S, H16, out);
    } else {
        k_finalize_mom<<<1, 64, 0, stream>>>(Wpre, gpre, bpre, S);
        k_stats2_fb<<<NBLK, 256, 0, stream>>>(poly, mask, Wpre, W1, S);
        k_finalize<<<1, 64, 0, stream>>>(g1, b1, S, 1);
        k_rec34<false><<<NBLK, 256, 0, stream>>>(poly, mask, Wpre, W1, W2, Wo1, bo1, Wo2, bo2, S, out);
        k_finalize<<<1, 64, 0, stream>>>(g2, b2, S, 2);
        k_rec34<true><<<NBLK, 256, 0, stream>>>(poly, mask, Wpre, W1, W2, Wo1, bo1, Wo2, bo2, S, out);
    }
}